// Round 1
// baseline (285.553 us; speedup 1.0000x reference)
//
#include <hip/hip_runtime.h>

#define NBINS   20
#define RSTRIDE 21          // 21 floats per replica: gcd(21,32)=1 -> lane->bank spread
#define NREP    64          // one histogram replica per lane id
#define NSETS   32          // replicated global accumulator slots (power of 2)
#define BLOCKS  2048
#define TPB     256

// ---------------- Pass 1: per-bin count + sum of squared error ----------------
__global__ __launch_bounds__(TPB, 8)
void dwmse_pass1(const float* __restrict__ pred, const float* __restrict__ targ,
                 float* __restrict__ ws, int n, int setMask)
{
    __shared__ float h[2 * NREP * RSTRIDE];   // [0..]: sse, [NREP*RSTRIDE..]: cnt
    const int tid  = threadIdx.x;
    const int lane = tid & 63;

    for (int i = tid; i < 2 * NREP * RSTRIDE; i += TPB) h[i] = 0.0f;
    __syncthreads();

    float* hs = h + lane * RSTRIDE;                 // my sse replica
    float* hc = h + NREP * RSTRIDE + lane * RSTRIDE; // my cnt replica

    const int n4 = n >> 2;
    const float4* p4 = reinterpret_cast<const float4*>(pred);
    const float4* t4 = reinterpret_cast<const float4*>(targ);
    const int idx0    = blockIdx.x * TPB + tid;
    const int gstride = gridDim.x * TPB;

    for (int i = idx0; i < n4; i += gstride) {
        float4 p = p4[i];
        float4 t = t4[i];
        {
            float d = p.x - t.x; float se = d * d;
            int b = (int)(t.x * 20.0f); b = min(max(b, 0), NBINS - 1);
            atomicAdd(&hs[b], se); atomicAdd(&hc[b], 1.0f);
        }
        {
            float d = p.y - t.y; float se = d * d;
            int b = (int)(t.y * 20.0f); b = min(max(b, 0), NBINS - 1);
            atomicAdd(&hs[b], se); atomicAdd(&hc[b], 1.0f);
        }
        {
            float d = p.z - t.z; float se = d * d;
            int b = (int)(t.z * 20.0f); b = min(max(b, 0), NBINS - 1);
            atomicAdd(&hs[b], se); atomicAdd(&hc[b], 1.0f);
        }
        {
            float d = p.w - t.w; float se = d * d;
            int b = (int)(t.w * 20.0f); b = min(max(b, 0), NBINS - 1);
            atomicAdd(&hs[b], se); atomicAdd(&hc[b], 1.0f);
        }
    }
    // scalar tail (empty for N = 2^24, kept for generality)
    for (int i = (n4 << 2) + idx0; i < n; i += gstride) {
        float t = targ[i];
        float d = pred[i] - t; float se = d * d;
        int b = (int)(t * 20.0f); b = min(max(b, 0), NBINS - 1);
        atomicAdd(&hs[b], se); atomicAdd(&hc[b], 1.0f);
    }

    __syncthreads();

    // reduce 64 replicas -> 20 bins, then one atomic per bin into a replicated slot
    if (tid < NBINS) {
        float ss = 0.0f, cc = 0.0f;
        #pragma unroll 8
        for (int r = 0; r < NREP; ++r) {
            ss += h[r * RSTRIDE + tid];
            cc += h[NREP * RSTRIDE + r * RSTRIDE + tid];
        }
        const int set = (int)(blockIdx.x) & setMask;
        unsafeAtomicAdd(&ws[set * 2 * NBINS + tid], ss);
        unsafeAtomicAdd(&ws[set * 2 * NBINS + NBINS + tid], cc);
    }
}

// ---------------- Pass 2: weights + final scalar ----------------
__global__ void dwmse_pass2(const float* __restrict__ ws, float* __restrict__ out,
                            int nsets, float inv_n)
{
    const int t = threadIdx.x;   // 64 threads = 1 wave
    float col = 0.0f;
    if (t < 2 * NBINS) {
        for (int s = 0; s < nsets; ++s) col += ws[s * 2 * NBINS + t];
    }
    // lanes 0..19 hold sse_b; counts live in lanes 20..39
    float sse = col;
    float cnt = __shfl(col, t + 20);

    float w = 0.0f;
    if (t < NBINS) {
        float c = fmaxf(cnt, 1.0f);
        w = __powf(c, -0.9f);
    }
    float s = w;
    #pragma unroll
    for (int off = 32; off > 0; off >>= 1) s += __shfl_down(s, off);
    s = __shfl(s, 0);

    float wb = (s > 0.0f) ? (w * (20.0f / s)) : w;
    wb = fmaxf(wb, 1.0f);

    float contrib = (t < NBINS) ? (wb * sse) : 0.0f;
    #pragma unroll
    for (int off = 32; off > 0; off >>= 1) contrib += __shfl_down(contrib, off);

    if (t == 0) out[0] = contrib * inv_n;
}

extern "C" void kernel_launch(void* const* d_in, const int* in_sizes, int n_in,
                              void* d_out, int out_size, void* d_ws, size_t ws_size,
                              hipStream_t stream)
{
    const float* pred = (const float*)d_in[0];
    const float* targ = (const float*)d_in[1];
    float*       out  = (float*)d_out;
    float*       ws   = (float*)d_ws;
    const int n = in_sizes[0];

    // replicated accumulator slots; shrink if workspace is tiny (pow2 kept)
    int nsets = NSETS;
    while ((size_t)nsets * 2 * NBINS * sizeof(float) > ws_size && nsets > 1) nsets >>= 1;

    hipMemsetAsync(d_ws, 0, (size_t)nsets * 2 * NBINS * sizeof(float), stream);
    dwmse_pass1<<<BLOCKS, TPB, 0, stream>>>(pred, targ, ws, n, nsets - 1);
    dwmse_pass2<<<1, 64, 0, stream>>>(ws, out, nsets, 1.0f / (float)n);
}

// Round 2
// 174.307 us; speedup vs baseline: 1.6382x; 1.6382x over previous
//
#include <hip/hip_runtime.h>

#define NBINS   20
#define NSETS   32          // replicated global accumulator slots (power of 2)
#define BLOCKS  2048
#define TPB     256
#define PACK    256.0f      // A = 256*cnt + sse ; per-thread cnt<=32, sse<32 -> exact decode

// ---------------- Pass 1: per-bin packed (count,sse) histogram ----------------
__global__ __launch_bounds__(TPB, 8)
void dwmse_pass1(const float* __restrict__ pred, const float* __restrict__ targ,
                 float* __restrict__ ws, int n, int setMask)
{
    // h[b*TPB + tid]: per-thread private accumulator. bank = tid%32 -> conflict-free.
    __shared__ float h[NBINS * TPB];     // 20 KB -> 8 blocks/CU
    const int tid = threadIdx.x;

    #pragma unroll
    for (int b = 0; b < NBINS; ++b) h[b * TPB + tid] = 0.0f;
    __syncthreads();

    const int n4 = n >> 2;
    const float4* p4 = reinterpret_cast<const float4*>(pred);
    const float4* t4 = reinterpret_cast<const float4*>(targ);
    const int idx0    = blockIdx.x * TPB + tid;
    const int gstride = gridDim.x * TPB;

    int i = idx0;
    if (i < n4) {
        float4 p = p4[i];
        float4 t = t4[i];
        for (;;) {
            const int j = i + gstride;
            const bool more = (j < n4);
            float4 pn, tn;
            if (more) { pn = p4[j]; tn = t4[j]; }   // prefetch overlaps LDS chains below

            {   float d = p.x - t.x; float a = fmaf(d, d, PACK);
                int b = min(max((int)(t.x * 20.0f), 0), NBINS - 1);
                h[b * TPB + tid] += a; }
            {   float d = p.y - t.y; float a = fmaf(d, d, PACK);
                int b = min(max((int)(t.y * 20.0f), 0), NBINS - 1);
                h[b * TPB + tid] += a; }
            {   float d = p.z - t.z; float a = fmaf(d, d, PACK);
                int b = min(max((int)(t.z * 20.0f), 0), NBINS - 1);
                h[b * TPB + tid] += a; }
            {   float d = p.w - t.w; float a = fmaf(d, d, PACK);
                int b = min(max((int)(t.w * 20.0f), 0), NBINS - 1);
                h[b * TPB + tid] += a; }

            if (!more) break;
            p = pn; t = tn; i = j;
        }
    }
    // scalar tail (empty for N = 2^24)
    for (int k = (n4 << 2) + idx0; k < n; k += gstride) {
        float t = targ[k];
        float d = pred[k] - t; float a = fmaf(d, d, PACK);
        int b = min(max((int)(t * 20.0f), 0), NBINS - 1);
        h[b * TPB + tid] += a;
    }

    __syncthreads();

    // ---- epilogue: decode per thread, butterfly per wave, combine per block ----
    const int lane = tid & 63;
    const int wv   = tid >> 6;              // 4 waves
    float my_sse = 0.0f, my_cnt = 0.0f;

    for (int b = 0; b < NBINS; ++b) {
        float A = h[b * TPB + tid];
        float c = floorf(A * (1.0f / 256.0f));   // exact: sse < 256
        float s = A - 256.0f * c;
        #pragma unroll
        for (int m = 32; m; m >>= 1) { c += __shfl_xor(c, m); s += __shfl_xor(s, m); }
        if (lane == b) { my_cnt = c; my_sse = s; }
    }
    __syncthreads();                         // everyone done reading h -> safe to reuse
    if (lane < NBINS) {
        h[wv * 2 * NBINS + lane]         = my_sse;
        h[wv * 2 * NBINS + NBINS + lane] = my_cnt;
    }
    __syncthreads();
    if (tid < NBINS) {
        float ss = 0.0f, cc = 0.0f;
        #pragma unroll
        for (int w = 0; w < TPB / 64; ++w) {
            ss += h[w * 2 * NBINS + tid];
            cc += h[w * 2 * NBINS + NBINS + tid];
        }
        const int set = (int)(blockIdx.x) & setMask;
        unsafeAtomicAdd(&ws[set * 2 * NBINS + tid], ss);
        unsafeAtomicAdd(&ws[set * 2 * NBINS + NBINS + tid], cc);
    }
}

// ---------------- Pass 2: weights + final scalar ----------------
__global__ void dwmse_pass2(const float* __restrict__ ws, float* __restrict__ out,
                            int nsets, float inv_n)
{
    const int t = threadIdx.x;   // 64 threads = 1 wave
    float col = 0.0f;
    if (t < 2 * NBINS) {
        for (int s = 0; s < nsets; ++s) col += ws[s * 2 * NBINS + t];
    }
    // lanes 0..19 hold sse_b; counts live in lanes 20..39
    float sse = col;
    float cnt = __shfl(col, t + 20);

    float w = 0.0f;
    if (t < NBINS) {
        float c = fmaxf(cnt, 1.0f);
        w = __powf(c, -0.9f);
    }
    float s = w;
    #pragma unroll
    for (int off = 32; off > 0; off >>= 1) s += __shfl_down(s, off);
    s = __shfl(s, 0);

    float wb = (s > 0.0f) ? (w * (20.0f / s)) : w;
    wb = fmaxf(wb, 1.0f);

    float contrib = (t < NBINS) ? (wb * sse) : 0.0f;
    #pragma unroll
    for (int off = 32; off > 0; off >>= 1) contrib += __shfl_down(contrib, off);

    if (t == 0) out[0] = contrib * inv_n;
}

extern "C" void kernel_launch(void* const* d_in, const int* in_sizes, int n_in,
                              void* d_out, int out_size, void* d_ws, size_t ws_size,
                              hipStream_t stream)
{
    const float* pred = (const float*)d_in[0];
    const float* targ = (const float*)d_in[1];
    float*       out  = (float*)d_out;
    float*       ws   = (float*)d_ws;
    const int n = in_sizes[0];

    int nsets = NSETS;
    while ((size_t)nsets * 2 * NBINS * sizeof(float) > ws_size && nsets > 1) nsets >>= 1;

    hipMemsetAsync(d_ws, 0, (size_t)nsets * 2 * NBINS * sizeof(float), stream);
    dwmse_pass1<<<BLOCKS, TPB, 0, stream>>>(pred, targ, ws, n, nsets - 1);
    dwmse_pass2<<<1, 64, 0, stream>>>(ws, out, nsets, 1.0f / (float)n);
}